// Round 5
// baseline (34.137 us; speedup 1.0000x reference)
//
#include <hip/hip_runtime.h>
#include <hip/hip_bf16.h>
#include <math.h>

// B=32768, L=24, H=64, V=64
#define B_SZ 32768
#define L_SZ 24
#define H_SZ 64
#define V_SZ 64

// Workspace (float offsets)
#define KN_WS 0        // kn[64][64]   normalized h rows
#define WK_WS 4096     // Wk[64][64]   h @ rp_w @ out_w rows
#define NRM_WS 8192    // ||h|| [64]
#define B2_WS 8256     // bias2[64]
#define CF_WS 8320     // cf[24] = 1 - alpha_t (cf[23]=0)
#define G_WS  8384     // Gram[64][64] = kn kn^T
#define WS_F  12480

// k_scan LDS (floats). Wk chunk-12: row stride 96, chunk s at 12*s ->
// 8 lanes of a group tile all 32 banks for ANY row (verified layout).
// c rows stride 28: group starts {0,28,24,20,16,12,8,4} -> conflict-free b128.
#define ROW 96
#define G_L    0        // G[64][64]
#define WK_L   4096     // Wk[64][96]
#define C_L    10240    // c[64][28]
#define TK_L   12032    // packed toks int[64][8]
#define TAIL_L 12544    // nrm[64], b2[64], cf[24] (+pad)
#define LDS_F  12704    // 50.8 KB

// ---------------------------------------------------------------------------
// Kernel A: fused table build (unchanged — validated R3/R4).
// ---------------------------------------------------------------------------
__global__ __launch_bounds__(64) void k_tab(
    const float* __restrict__ embed, const float* __restrict__ w1, const float* __restrict__ b1,
    const float* __restrict__ w2, const float* __restrict__ b2,
    const float* __restrict__ ln_g, const float* __restrict__ ln_b,
    const float* __restrict__ rp_w, const float* __restrict__ rp_b,
    const float* __restrict__ out_w, const float* __restrict__ out_b,
    const float* __restrict__ alpha_logits, float* __restrict__ ws)
{
  const int v = blockIdx.x;
  const int j = threadIdx.x;

  if (v < V_SZ) {
    const float ev = embed[v * H_SZ + j];
    float h0 = b1[j], h1 = b1[j + 64];
    #pragma unroll
    for (int k = 0; k < H_SZ; ++k) {
      const float ek = __shfl(ev, k);
      h0 = fmaf(ek, w1[k * 128 + j], h0);
      h1 = fmaf(ek, w1[k * 128 + 64 + j], h1);
    }
    h0 = fmaxf(h0, 0.0f);
    h1 = fmaxf(h1, 0.0f);
    float x = ev + b2[j];
    #pragma unroll
    for (int k = 0; k < H_SZ; ++k) {
      x = fmaf(__shfl(h0, k), w2[k * H_SZ + j], x);
      x = fmaf(__shfl(h1, k), w2[(k + 64) * H_SZ + j], x);
    }
    float mu = x;
    #pragma unroll
    for (int m = 1; m < 64; m <<= 1) mu += __shfl_xor(mu, m);
    mu *= (1.0f / 64.0f);
    const float dv = x - mu;
    float var = dv * dv;
    #pragma unroll
    for (int m = 1; m < 64; m <<= 1) var += __shfl_xor(var, m);
    var *= (1.0f / 64.0f);
    const float y = dv * rsqrtf(var + 1e-5f) * ln_g[j] + ln_b[j];
    float n2 = y * y;
    #pragma unroll
    for (int m = 1; m < 64; m <<= 1) n2 += __shfl_xor(n2, m);
    const float nrm = sqrtf(n2);
    const float rn = 1.0f / fmaxf(nrm, 1e-12f);
    ws[KN_WS + v * H_SZ + j] = y * rn;
    if (j == 0) ws[NRM_WS + v] = nrm;
    float t1 = 0.0f;
    #pragma unroll
    for (int k = 0; k < H_SZ; ++k) t1 = fmaf(__shfl(y, k), rp_w[k * H_SZ + j], t1);
    float wk = 0.0f;
    #pragma unroll
    for (int k = 0; k < H_SZ; ++k) wk = fmaf(__shfl(t1, k), out_w[k * V_SZ + j], wk);
    ws[WK_WS + v * H_SZ + j] = wk;
  } else {
    float s = out_b[j];
    #pragma unroll
    for (int k = 0; k < H_SZ; ++k) s = fmaf(rp_b[k], out_w[k * V_SZ + j], s);
    ws[B2_WS + j] = s;
    if (j < L_SZ) {
      float cf = 0.0f;
      if (j < L_SZ - 1) {
        const float a = 1.0f / (1.0f + expf(-alpha_logits[j])) * 0.49f + 0.5f;
        cf = 1.0f - a;
      }
      ws[CF_WS + j] = cf;
    }
  }
}

// ---------------------------------------------------------------------------
// Kernel B: Gram table (unchanged — validated R4).
// ---------------------------------------------------------------------------
__global__ __launch_bounds__(64) void k_gram(float* __restrict__ ws)
{
  const int u = blockIdx.x;
  const int j = threadIdx.x;
  const float a = ws[KN_WS + u * H_SZ + j];
  float r[64];
  const float4* rp = (const float4*)(ws + KN_WS + j * H_SZ);
  #pragma unroll
  for (int i = 0; i < 16; ++i) {
    const float4 f = rp[i];
    r[4 * i] = f.x; r[4 * i + 1] = f.y; r[4 * i + 2] = f.z; r[4 * i + 3] = f.w;
  }
  float s = 0.0f;
  #pragma unroll
  for (int k = 0; k < 64; ++k) s = fmaf(__shfl(a, k), r[k], s);
  ws[G_WS + u * H_SZ + j] = s;
}

// ---------------------------------------------------------------------------
// Kernel C: scan. 1 wave per block, 64 batches/block (1 per lane in phase A),
// grid 512. Phase A: scalar Gram recursion, all 64 lanes. Phase B: 8 groups
// of 8 lanes, 8 iters; c via 6 conflict-free b128 + toks via 2 b128.
// ---------------------------------------------------------------------------
__global__ __launch_bounds__(64) void k_scan(
    const int* __restrict__ seq, const float* __restrict__ ws, float* __restrict__ out)
{
  __shared__ float lds[LDS_F];
  const int lane = threadIdx.x;
  const float4* ws4 = (const float4*)ws;

  // Stage G (linear), Wk (chunk-12 relayout), tail (nrm|b2|cf).
  float4* g4 = (float4*)(lds + G_L);
  for (int i = lane; i < 1024; i += 64) g4[i] = ws4[G_WS / 4 + i];
  for (int i = lane; i < 1024; i += 64) {
    const float4 f = ws4[WK_WS / 4 + i];
    const int r = i >> 4;
    const int c4 = (i & 15) * 4;                       // 0,4,...,60
    *(float4*)(lds + WK_L + r * ROW + 12 * (c4 >> 3) + (c4 & 4)) = f;
  }
  if (lane < 38) ((float4*)(lds + TAIL_L))[lane] = ws4[NRM_WS / 4 + lane];
  __syncthreads();

  const float* nrmL = lds + TAIL_L;
  const float* b2L  = lds + TAIL_L + 64;
  const float* cfL  = lds + TAIL_L + 128;
  const float* Gt   = lds + G_L;

  // ---- Phase A: one batch per lane ----
  const int batch0 = blockIdx.x * 64;
  {
    const int batch = batch0 + lane;
    int g[24];
    const int4* sp = (const int4*)(seq + batch * L_SZ);
    #pragma unroll
    for (int i = 0; i < 6; ++i) {
      const int4 t4 = sp[i];
      g[4 * i] = t4.x; g[4 * i + 1] = t4.y; g[4 * i + 2] = t4.z; g[4 * i + 3] = t4.w;
    }
    // packed tokens -> LDS (2 x int4)
    int tw[8];
    #pragma unroll
    for (int i = 0; i < 6; ++i)
      tw[i] = g[4 * i] | (g[4 * i + 1] << 8) | (g[4 * i + 2] << 16) | (g[4 * i + 3] << 24);
    tw[6] = 0; tw[7] = 0;
    int* tkb = (int*)lds + TK_L + lane * 8;
    ((int4*)tkb)[0] = make_int4(tw[0], tw[1], tw[2], tw[3]);
    ((int4*)tkb)[1] = make_int4(tw[4], tw[5], tw[6], tw[7]);

    // cf broadcast into regs
    float cfv[24];
    #pragma unroll
    for (int i = 0; i < 6; ++i) {
      const float4 f = ((const float4*)cfL)[i];
      cfv[4 * i] = f.x; cfv[4 * i + 1] = f.y; cfv[4 * i + 2] = f.z; cfv[4 * i + 3] = f.w;
    }

    const int q = g[23];
    const float nl = nrmL[q];
    float P[23], carr[24];
    #pragma unroll
    for (int t = 0; t < 23; ++t) P[t] = 0.0f;
    #pragma unroll
    for (int s = 22; s >= 0; --s) {
      const float base = nl * Gt[(g[s] << 6) + q];
      const float cs = cfv[s] * (base - P[s]);
      carr[s] = cs;
      #pragma unroll
      for (int t = 0; t < s; ++t)
        P[t] = fmaf(cs, Gt[(g[t] << 6) + g[s]], P[t]);
    }
    carr[23] = 0.0f;
    float* cb = lds + C_L + lane * 28;
    #pragma unroll
    for (int i = 0; i < 6; ++i)
      ((float4*)cb)[i] = make_float4(carr[4 * i], carr[4 * i + 1], carr[4 * i + 2], carr[4 * i + 3]);
  }
  __syncthreads();

  // ---- Phase B: 8 groups x 8 lanes, 8 iterations ----
  const int grp = lane >> 3;
  const int s8 = lane & 7;
  const int cb12 = 12 * s8;
  const float4 bA = ((const float4*)(b2L + s8 * 8))[0];
  const float4 bB = ((const float4*)(b2L + s8 * 8))[1];
  const float* wkL = lds + WK_L;

  #pragma unroll
  for (int it = 0; it < 8; ++it) {
    const int ab = it * 8 + grp;
    // c broadcast (6 x b128, conflict-free across groups)
    float cv[24];
    const float4* cp = (const float4*)(lds + C_L + ab * 28);
    #pragma unroll
    for (int i = 0; i < 6; ++i) {
      const float4 f = cp[i];
      cv[4 * i] = f.x; cv[4 * i + 1] = f.y; cv[4 * i + 2] = f.z; cv[4 * i + 3] = f.w;
    }
    // packed toks (2 x b128 broadcast)
    const int4* tp = (const int4*)((const int*)lds + TK_L + ab * 8);
    const int4 ta = tp[0], tb = tp[1];
    int tw[6] = {ta.x, ta.y, ta.z, ta.w, tb.x, tb.y};

    float oa[8] = {bA.x, bA.y, bA.z, bA.w, bB.x, bB.y, bB.z, bB.w};
    #pragma unroll
    for (int t = 0; t < 23; ++t) {
      const float c = cv[t];
      const int tok = (tw[t >> 2] >> ((t & 3) * 8)) & 63;
      const float* wr = wkL + tok * ROW + cb12;
      const float4 wa = *(const float4*)wr;
      const float4 wb = *(const float4*)(wr + 4);
      oa[0] = fmaf(c, wa.x, oa[0]); oa[1] = fmaf(c, wa.y, oa[1]);
      oa[2] = fmaf(c, wa.z, oa[2]); oa[3] = fmaf(c, wa.w, oa[3]);
      oa[4] = fmaf(c, wb.x, oa[4]); oa[5] = fmaf(c, wb.y, oa[5]);
      oa[6] = fmaf(c, wb.z, oa[6]); oa[7] = fmaf(c, wb.w, oa[7]);
    }
    float4* op = (float4*)(out + (batch0 + ab) * V_SZ + s8 * 8);
    op[0] = make_float4(oa[0], oa[1], oa[2], oa[3]);
    op[1] = make_float4(oa[4], oa[5], oa[6], oa[7]);
  }
}

// ---------------------------------------------------------------------------
extern "C" void kernel_launch(void* const* d_in, const int* in_sizes, int n_in,
                              void* d_out, int out_size, void* d_ws, size_t ws_size,
                              hipStream_t stream)
{
  const int*   seq          = (const int*)d_in[0];
  const float* embed        = (const float*)d_in[1];
  const float* w1           = (const float*)d_in[2];
  const float* b1           = (const float*)d_in[3];
  const float* w2           = (const float*)d_in[4];
  const float* b2           = (const float*)d_in[5];
  const float* ln_g         = (const float*)d_in[6];
  const float* ln_b         = (const float*)d_in[7];
  const float* rp_w         = (const float*)d_in[8];
  const float* rp_b         = (const float*)d_in[9];
  const float* out_w        = (const float*)d_in[10];
  const float* out_b        = (const float*)d_in[11];
  const float* alpha_logits = (const float*)d_in[12];
  float* ws   = (float*)d_ws;
  float* outp = (float*)d_out;

  hipLaunchKernelGGL(k_tab, dim3(V_SZ + 1), dim3(64), 0, stream,
                     embed, w1, b1, w2, b2, ln_g, ln_b,
                     rp_w, rp_b, out_w, out_b, alpha_logits, ws);
  hipLaunchKernelGGL(k_gram, dim3(V_SZ), dim3(64), 0, stream, ws);
  hipLaunchKernelGGL(k_scan, dim3(B_SZ / 64), dim3(64), 0, stream,
                     seq, ws, outp);
}

// Round 6
// 32.122 us; speedup vs baseline: 1.0627x; 1.0627x over previous
//
#include <hip/hip_runtime.h>
#include <hip/hip_bf16.h>
#include <math.h>

// B=32768, L=24, H=64, V=64
#define B_SZ 32768
#define L_SZ 24
#define H_SZ 64
#define V_SZ 64

// Workspace (float offsets)
#define KN_WS 0        // kn[64][64]
#define WK_WS 4096     // Wk[64][64]
#define NRM_WS 8192    // ||h|| [64]
#define B2_WS 8256     // bias2[64]
#define CF_WS 8320     // cf[24] (cf[23]=0)
#define G_WS  8384     // Gram, column-swizzled: G[u][(v+u)&63] = kn[u].kn[v]
#define WS_F  12480

// k_scan LDS (floats)
#define ROW 96         // Wk chunk-12 layout: row 96, chunk s at 12*s
#define G_L    0       // G[64][64] (swizzled)
#define WK_L   4096    // Wk[64][96]
#define C_L    10240   // c[64][28]
#define TK_L   12032   // packed toks int[64][8]
#define TAIL_L 12544   // nrm[64] | b2[64] | cf[24]
#define LDS_F  12704   // 50.8 KB -> 3 blocks/CU

// ---------------------------------------------------------------------------
// Kernel A: fused table build (validated R3-R5).
// ---------------------------------------------------------------------------
__global__ __launch_bounds__(64) void k_tab(
    const float* __restrict__ embed, const float* __restrict__ w1, const float* __restrict__ b1,
    const float* __restrict__ w2, const float* __restrict__ b2,
    const float* __restrict__ ln_g, const float* __restrict__ ln_b,
    const float* __restrict__ rp_w, const float* __restrict__ rp_b,
    const float* __restrict__ out_w, const float* __restrict__ out_b,
    const float* __restrict__ alpha_logits, float* __restrict__ ws)
{
  const int v = blockIdx.x;
  const int j = threadIdx.x;

  if (v < V_SZ) {
    const float ev = embed[v * H_SZ + j];
    float h0 = b1[j], h1 = b1[j + 64];
    #pragma unroll
    for (int k = 0; k < H_SZ; ++k) {
      const float ek = __shfl(ev, k);
      h0 = fmaf(ek, w1[k * 128 + j], h0);
      h1 = fmaf(ek, w1[k * 128 + 64 + j], h1);
    }
    h0 = fmaxf(h0, 0.0f);
    h1 = fmaxf(h1, 0.0f);
    float x = ev + b2[j];
    #pragma unroll
    for (int k = 0; k < H_SZ; ++k) {
      x = fmaf(__shfl(h0, k), w2[k * H_SZ + j], x);
      x = fmaf(__shfl(h1, k), w2[(k + 64) * H_SZ + j], x);
    }
    float mu = x;
    #pragma unroll
    for (int m = 1; m < 64; m <<= 1) mu += __shfl_xor(mu, m);
    mu *= (1.0f / 64.0f);
    const float dv = x - mu;
    float var = dv * dv;
    #pragma unroll
    for (int m = 1; m < 64; m <<= 1) var += __shfl_xor(var, m);
    var *= (1.0f / 64.0f);
    const float y = dv * rsqrtf(var + 1e-5f) * ln_g[j] + ln_b[j];
    float n2 = y * y;
    #pragma unroll
    for (int m = 1; m < 64; m <<= 1) n2 += __shfl_xor(n2, m);
    const float nrm = sqrtf(n2);
    const float rn = 1.0f / fmaxf(nrm, 1e-12f);
    ws[KN_WS + v * H_SZ + j] = y * rn;
    if (j == 0) ws[NRM_WS + v] = nrm;
    float t1 = 0.0f;
    #pragma unroll
    for (int k = 0; k < H_SZ; ++k) t1 = fmaf(__shfl(y, k), rp_w[k * H_SZ + j], t1);
    float wk = 0.0f;
    #pragma unroll
    for (int k = 0; k < H_SZ; ++k) wk = fmaf(__shfl(t1, k), out_w[k * V_SZ + j], wk);
    ws[WK_WS + v * H_SZ + j] = wk;
  } else {
    float s = out_b[j];
    #pragma unroll
    for (int k = 0; k < H_SZ; ++k) s = fmaf(rp_b[k], out_w[k * V_SZ + j], s);
    ws[B2_WS + j] = s;
    if (j < L_SZ) {
      float cf = 0.0f;
      if (j < L_SZ - 1) {
        const float a = 1.0f / (1.0f + expf(-alpha_logits[j])) * 0.49f + 0.5f;
        cf = 1.0f - a;
      }
      ws[CF_WS + j] = cf;
    }
  }
}

// ---------------------------------------------------------------------------
// Kernel B: Gram table, COLUMN-SWIZZLED: ws[G + u*64 + ((j+u)&63)] = kn[u].kn[j]
// (swizzle decorrelates LDS banks for the quad-split gathers in k_scan).
// ---------------------------------------------------------------------------
__global__ __launch_bounds__(64) void k_gram(float* __restrict__ ws)
{
  const int u = blockIdx.x;
  const int j = threadIdx.x;
  const float a = ws[KN_WS + u * H_SZ + j];
  float r[64];
  const float4* rp = (const float4*)(ws + KN_WS + j * H_SZ);
  #pragma unroll
  for (int i = 0; i < 16; ++i) {
    const float4 f = rp[i];
    r[4 * i] = f.x; r[4 * i + 1] = f.y; r[4 * i + 2] = f.z; r[4 * i + 3] = f.w;
  }
  float s = 0.0f;
  #pragma unroll
  for (int k = 0; k < 64; ++k) s = fmaf(__shfl(a, k), r[k], s);
  ws[G_WS + u * H_SZ + ((j + u) & 63)] = s;
}

// ---------------------------------------------------------------------------
// DPP quad broadcast: all 4 lanes of each quad get lane K's value (VALU-only).
// ---------------------------------------------------------------------------
template<int K>
__device__ __forceinline__ float qbcast(float x) {
  return __int_as_float(__builtin_amdgcn_mov_dpp(
      __float_as_int(x), (K * 0x55) & 0xFF, 0xF, 0xF, true));
}

// token S of this batch (compile-time S -> folds to one component)
#define GTOK(S) ((((S) & 3) == 0) ? t4[(S) >> 2].x : \
                 (((S) & 3) == 1) ? t4[(S) >> 2].y : \
                 (((S) & 3) == 2) ? t4[(S) >> 2].z : t4[(S) >> 2].w)

// ---------------------------------------------------------------------------
// Kernel C: scan. 256 thr, 64 batches/block, grid 512 (all waves resident,
// 3 blocks/CU capacity). Phase A: quad-split Gram recursion (4 lanes/batch,
// triangle gathers distributed by t mod 4, c_s broadcast via DPP quad_perm).
// Phase B: validated chunk-12 f32 Wk accumulation (bank-optimal b128s).
// ---------------------------------------------------------------------------
__global__ __launch_bounds__(256) void k_scan(
    const int* __restrict__ seq, const float* __restrict__ ws, float* __restrict__ out)
{
  __shared__ float lds[LDS_F];
  const int tid = threadIdx.x;
  const float4* ws4 = (const float4*)ws;

  // Stage G (pre-swizzled, linear copy), Wk (chunk-12 relayout), tail.
  for (int i = tid; i < 1024; i += 256)
    ((float4*)(lds + G_L))[i] = ws4[G_WS / 4 + i];
  for (int i = tid; i < 1024; i += 256) {
    const float4 f = ws4[WK_WS / 4 + i];
    const int r = i >> 4;
    const int c4 = (i & 15) * 4;
    *(float4*)(lds + WK_L + r * ROW + 12 * (c4 >> 3) + (c4 & 7)) = f;
  }
  if (tid < 38) ((float4*)(lds + TAIL_L))[tid] = ws4[NRM_WS / 4 + tid];
  __syncthreads();

  const float* Gl   = lds + G_L;
  const float* nrmL = lds + TAIL_L;
  const float* b2L  = lds + TAIL_L + 64;
  const float* cfL  = lds + TAIL_L + 128;

  const int lane = tid & 63;
  const int wv   = tid >> 6;
  const int q4   = lane & 3;         // quad lane
  const int qb   = lane >> 2;        // batch within wave (0..15)
  const int ab   = wv * 16 + qb;     // batch within block
  const int batch0 = blockIdx.x * 64;

  // ---- Phase A: quad-split backward Gram recursion ----
  {
    const int4* sp = (const int4*)(seq + (batch0 + ab) * L_SZ);
    int4 t4[6];
    #pragma unroll
    for (int i = 0; i < 6; ++i) t4[i] = sp[i];

    // own tokens (t = q4 + 4i) via compile-time quad selects; own G row bases
    int go[6], rowb[6];
    #pragma unroll
    for (int i = 0; i < 6; ++i) {
      int x = t4[i].x;
      x = (q4 == 1) ? t4[i].y : x;
      x = (q4 == 2) ? t4[i].z : x;
      x = (q4 == 3) ? t4[i].w : x;
      go[i] = x; rowb[i] = x << 6;
    }
    const int q = t4[5].w;
    const float nl = nrmL[q];

    float cfv[24];
    #pragma unroll
    for (int i = 0; i < 6; ++i) {
      const float4 f = ((const float4*)cfL)[i];
      cfv[4 * i] = f.x; cfv[4 * i + 1] = f.y; cfv[4 * i + 2] = f.z; cfv[4 * i + 3] = f.w;
    }

    // P[i] = running partial for t = q4 + 4i (single owner per t)
    float P[6] = {0.f, 0.f, 0.f, 0.f, 0.f, 0.f};
    float carr[24];
    carr[23] = 0.f;

#define STEPA(S) { \
    const int gS = GTOK(S); \
    const float bse = nl * Gl[(gS << 6) | ((q + gS) & 63)]; \
    const float As = qbcast<(S) & 3>(bse - P[(S) >> 2]); \
    const float cs = cfv[(S)] * As; \
    carr[(S)] = cs; \
    _Pragma("unroll") \
    for (int i = 0; i < 6; ++i) { \
      if (q4 + 4 * i < (S)) \
        P[i] = fmaf(cs, Gl[rowb[i] | ((gS + go[i]) & 63)], P[i]); \
    } \
  }
    STEPA(22) STEPA(21) STEPA(20) STEPA(19) STEPA(18) STEPA(17)
    STEPA(16) STEPA(15) STEPA(14) STEPA(13) STEPA(12) STEPA(11)
    STEPA(10) STEPA(9)  STEPA(8)  STEPA(7)  STEPA(6)  STEPA(5)
    STEPA(4)  STEPA(3)  STEPA(2)  STEPA(1)  STEPA(0)
#undef STEPA

    if (q4 == 0) {                       // one lane per batch writes c + toks
      float* cb = lds + C_L + ab * 28;
      #pragma unroll
      for (int i = 0; i < 6; ++i)
        ((float4*)cb)[i] = make_float4(carr[4 * i], carr[4 * i + 1],
                                       carr[4 * i + 2], carr[4 * i + 3]);
      int tw[6];
      #pragma unroll
      for (int i = 0; i < 6; ++i)
        tw[i] = t4[i].x | (t4[i].y << 8) | (t4[i].z << 16) | (t4[i].w << 24);
      int* tkb = (int*)lds + TK_L + ab * 8;
      ((int4*)tkb)[0] = make_int4(tw[0], tw[1], tw[2], tw[3]);
      ((int4*)tkb)[1] = make_int4(tw[4], tw[5], 0, 0);
    }
  }
  __syncthreads();

  // ---- Phase B: out[b] = b2 + sum_t c_t * Wk[g_t] (chunk-12, bank-optimal) ----
  const int grp = lane >> 3;
  const int s8  = lane & 7;
  const int cb12 = 12 * s8;
  const float4 bA = ((const float4*)(b2L + s8 * 8))[0];
  const float4 bB = ((const float4*)(b2L + s8 * 8))[1];
  const float* wkL = lds + WK_L;

  #pragma unroll
  for (int it = 0; it < 2; ++it) {
    const int abb = wv * 16 + it * 8 + grp;
    float cv[24];
    const float4* cp = (const float4*)(lds + C_L + abb * 28);
    #pragma unroll
    for (int i = 0; i < 6; ++i) {
      const float4 f = cp[i];
      cv[4 * i] = f.x; cv[4 * i + 1] = f.y; cv[4 * i + 2] = f.z; cv[4 * i + 3] = f.w;
    }
    const int4* tp = (const int4*)((const int*)lds + TK_L + abb * 8);
    const int4 ta = tp[0], tb = tp[1];
    int tw[6] = {ta.x, ta.y, ta.z, ta.w, tb.x, tb.y};

    float oa[8] = {bA.x, bA.y, bA.z, bA.w, bB.x, bB.y, bB.z, bB.w};
    #pragma unroll
    for (int t = 0; t < 23; ++t) {
      const float c = cv[t];
      const int tok = (tw[t >> 2] >> ((t & 3) * 8)) & 63;
      const float* wr = wkL + tok * ROW + cb12;
      const float4 wa = *(const float4*)wr;
      const float4 wb = *(const float4*)(wr + 4);
      oa[0] = fmaf(c, wa.x, oa[0]); oa[1] = fmaf(c, wa.y, oa[1]);
      oa[2] = fmaf(c, wa.z, oa[2]); oa[3] = fmaf(c, wa.w, oa[3]);
      oa[4] = fmaf(c, wb.x, oa[4]); oa[5] = fmaf(c, wb.y, oa[5]);
      oa[6] = fmaf(c, wb.z, oa[6]); oa[7] = fmaf(c, wb.w, oa[7]);
    }
    float4* op = (float4*)(out + (batch0 + abb) * V_SZ + s8 * 8);
    op[0] = make_float4(oa[0], oa[1], oa[2], oa[3]);
    op[1] = make_float4(oa[4], oa[5], oa[6], oa[7]);
  }
}

// ---------------------------------------------------------------------------
extern "C" void kernel_launch(void* const* d_in, const int* in_sizes, int n_in,
                              void* d_out, int out_size, void* d_ws, size_t ws_size,
                              hipStream_t stream)
{
  const int*   seq          = (const int*)d_in[0];
  const float* embed        = (const float*)d_in[1];
  const float* w1           = (const float*)d_in[2];
  const float* b1           = (const float*)d_in[3];
  const float* w2           = (const float*)d_in[4];
  const float* b2           = (const float*)d_in[5];
  const float* ln_g         = (const float*)d_in[6];
  const float* ln_b         = (const float*)d_in[7];
  const float* rp_w         = (const float*)d_in[8];
  const float* rp_b         = (const float*)d_in[9];
  const float* out_w        = (const float*)d_in[10];
  const float* out_b        = (const float*)d_in[11];
  const float* alpha_logits = (const float*)d_in[12];
  float* ws   = (float*)d_ws;
  float* outp = (float*)d_out;

  hipLaunchKernelGGL(k_tab, dim3(V_SZ + 1), dim3(64), 0, stream,
                     embed, w1, b1, w2, b2, ln_g, ln_b,
                     rp_w, rp_b, out_w, out_b, alpha_logits, ws);
  hipLaunchKernelGGL(k_gram, dim3(V_SZ), dim3(64), 0, stream, ws);
  hipLaunchKernelGGL(k_scan, dim3(B_SZ / 64), dim3(256), 0, stream,
                     seq, ws, outp);
}

// Round 7
// 29.858 us; speedup vs baseline: 1.1433x; 1.0758x over previous
//
#include <hip/hip_runtime.h>
#include <hip/hip_bf16.h>
#include <math.h>

// B=32768, L=24, H=64, V=64
#define B_SZ 32768
#define L_SZ 24
#define H_SZ 64
#define V_SZ 64

// ws layout (dword offsets). [G|WKTH|WKTL|TAIL] is contiguous so the scan
// stages it with one linear copy.
#define KN_O    0        // kn[64][64] f32 (scratch for k_gw)
#define WK_O    4096     // Wk[64][64] f32 (scratch for k_gw)
#define G_O     8192     // G[64][64] f32 = kn kn^T
#define WKTH_O  12288    // WkT hi bf16 [64 cols][72] (36 dw/row, 16B-aligned rows)
#define WKTL_O  14592    // WkT lo bf16 [64][72]
#define TAIL_O  16896    // nrm[64] | b2[64] | cf[32]
#define WS_DW   17056

// scan LDS layout (dwords): staged mirror of dw [8192..17055] then W buffers
#define G_L     0
#define WKTH_L  4096
#define WKTL_L  6400
#define TAIL_L  8704
#define W32_L   8864     // W accum f32 [64][64]
#define WH_L    12960    // W hi bf16 [64][72]
#define WL_L    15264    // W lo bf16 [64][72]
#define LDS_DW  17568    // 70.3 KB -> 2 blocks/CU (8 waves/CU)

typedef __attribute__((ext_vector_type(8))) short short8v;   // 8 bf16
typedef __attribute__((ext_vector_type(4))) float f32x4;

static __device__ __forceinline__ unsigned short bf_hi(float x) {
  const unsigned b = __float_as_uint(x);
  return (unsigned short)((b + 0x7FFF + ((b >> 16) & 1)) >> 16);  // RNE
}

// ---------------------------------------------------------------------------
// Kernel A: table build (validated R3-R6; only ws offsets changed).
// Blocks 0..63: row v -> kn, Wk, nrm. Block 64: bias2 + cf.
// ---------------------------------------------------------------------------
__global__ __launch_bounds__(64) void k_tab(
    const float* __restrict__ embed, const float* __restrict__ w1, const float* __restrict__ b1,
    const float* __restrict__ w2, const float* __restrict__ b2,
    const float* __restrict__ ln_g, const float* __restrict__ ln_b,
    const float* __restrict__ rp_w, const float* __restrict__ rp_b,
    const float* __restrict__ out_w, const float* __restrict__ out_b,
    const float* __restrict__ alpha_logits, float* __restrict__ ws)
{
  const int v = blockIdx.x;
  const int j = threadIdx.x;

  if (v < V_SZ) {
    const float ev = embed[v * H_SZ + j];
    float h0 = b1[j], h1 = b1[j + 64];
    #pragma unroll
    for (int k = 0; k < H_SZ; ++k) {
      const float ek = __shfl(ev, k);
      h0 = fmaf(ek, w1[k * 128 + j], h0);
      h1 = fmaf(ek, w1[k * 128 + 64 + j], h1);
    }
    h0 = fmaxf(h0, 0.0f);
    h1 = fmaxf(h1, 0.0f);
    float x = ev + b2[j];
    #pragma unroll
    for (int k = 0; k < H_SZ; ++k) {
      x = fmaf(__shfl(h0, k), w2[k * H_SZ + j], x);
      x = fmaf(__shfl(h1, k), w2[(k + 64) * H_SZ + j], x);
    }
    float mu = x;
    #pragma unroll
    for (int m = 1; m < 64; m <<= 1) mu += __shfl_xor(mu, m);
    mu *= (1.0f / 64.0f);
    const float dv = x - mu;
    float var = dv * dv;
    #pragma unroll
    for (int m = 1; m < 64; m <<= 1) var += __shfl_xor(var, m);
    var *= (1.0f / 64.0f);
    const float y = dv * rsqrtf(var + 1e-5f) * ln_g[j] + ln_b[j];
    float n2 = y * y;
    #pragma unroll
    for (int m = 1; m < 64; m <<= 1) n2 += __shfl_xor(n2, m);
    const float nrm = sqrtf(n2);
    const float rn = 1.0f / fmaxf(nrm, 1e-12f);
    ws[KN_O + v * H_SZ + j] = y * rn;
    if (j == 0) ws[TAIL_O + v] = nrm;
    float t1 = 0.0f;
    #pragma unroll
    for (int k = 0; k < H_SZ; ++k) t1 = fmaf(__shfl(y, k), rp_w[k * H_SZ + j], t1);
    float wk = 0.0f;
    #pragma unroll
    for (int k = 0; k < H_SZ; ++k) wk = fmaf(__shfl(t1, k), out_w[k * V_SZ + j], wk);
    ws[WK_O + v * H_SZ + j] = wk;
  } else {
    float s = out_b[j];
    #pragma unroll
    for (int k = 0; k < H_SZ; ++k) s = fmaf(rp_b[k], out_w[k * V_SZ + j], s);
    ws[TAIL_O + 64 + j] = s;
    if (j < 32) {
      float cf = 0.0f;
      if (j < L_SZ - 1) {
        const float a = 1.0f / (1.0f + expf(-alpha_logits[j])) * 0.49f + 0.5f;
        cf = 1.0f - a;
      }
      ws[TAIL_O + 128 + j] = cf;
    }
  }
}

// ---------------------------------------------------------------------------
// Kernel B: block u computes Gram row u (validated k_gram code) AND the
// bf16 hi/lo split of WkT column u (strided read of Wk, coalesced write).
// ---------------------------------------------------------------------------
__global__ __launch_bounds__(64) void k_gw(float* __restrict__ ws)
{
  const int u = blockIdx.x;
  const int j = threadIdx.x;
  const float a = ws[KN_O + u * H_SZ + j];
  float r[64];
  const float4* rp = (const float4*)(ws + KN_O + j * H_SZ);
  #pragma unroll
  for (int i = 0; i < 16; ++i) {
    const float4 f = rp[i];
    r[4 * i] = f.x; r[4 * i + 1] = f.y; r[4 * i + 2] = f.z; r[4 * i + 3] = f.w;
  }
  float s = 0.0f;
  #pragma unroll
  for (int k = 0; k < 64; ++k) s = fmaf(__shfl(a, k), r[k], s);
  ws[G_O + u * H_SZ + j] = s;

  // WkT[u][j] = Wk[j][u], split hi/lo
  const float x = ws[WK_O + j * H_SZ + u];
  const unsigned short hi = bf_hi(x);
  const float fhi = __uint_as_float((unsigned)hi << 16);
  const unsigned short lo = bf_hi(x - fhi);
  unsigned short* wsu = (unsigned short*)ws;
  wsu[WKTH_O * 2 + u * 72 + j] = hi;
  wsu[WKTL_O * 2 + u * 72 + j] = lo;
}

// ---------------------------------------------------------------------------
// Kernel C: scan. 256 thr, 64 batches/block, grid 512 (2 blocks/CU exact).
// Phase A (16 lanes/wave): scalar Gram recursion (validated R4) + ds_add_f32
// scatter of c_t into W32[batch][token] (collision-safe, single owner lane).
// Convert: W32 -> bf16 hi/lo. Phase B: out = b2 + W @ WkT via 24 MFMAs/wave
// (split-precision: hh + lh + hl; dropped ll term ~2^-18 rel).
// ---------------------------------------------------------------------------
__global__ __launch_bounds__(256) void k_scan(
    const int* __restrict__ seq, const float* __restrict__ ws, float* __restrict__ out)
{
  __shared__ float lds[LDS_DW];
  const int tid = threadIdx.x;
  const float4* ws4 = (const float4*)ws;
  float4* l4 = (float4*)lds;
  for (int i = tid; i < (WS_DW - 8192) / 4; i += 256) l4[i] = ws4[2048 + i];
  const float4 z4 = {0.f, 0.f, 0.f, 0.f};
  for (int i = tid; i < 1024; i += 256) ((float4*)(lds + W32_L))[i] = z4;
  __syncthreads();

  const int lane = tid & 63;
  const int wv = tid >> 6;
  const int batch0 = blockIdx.x * 64;
  const float* Gt = lds + G_L;

  // ---- Phase A ----
  if (lane < 16) {
    const int ab = wv * 16 + lane;
    int g[24];
    const int4* sp = (const int4*)(seq + (batch0 + ab) * L_SZ);
    #pragma unroll
    for (int i = 0; i < 6; ++i) {
      const int4 t4 = sp[i];
      g[4 * i] = t4.x; g[4 * i + 1] = t4.y; g[4 * i + 2] = t4.z; g[4 * i + 3] = t4.w;
    }
    const int q = g[23];
    const float nl = lds[TAIL_L + q];
    float cfv[24];
    #pragma unroll
    for (int i = 0; i < 6; ++i) {
      const float4 f = ((const float4*)(lds + TAIL_L + 128))[i];
      cfv[4 * i] = f.x; cfv[4 * i + 1] = f.y; cfv[4 * i + 2] = f.z; cfv[4 * i + 3] = f.w;
    }
    float P[23], carr[23];
    #pragma unroll
    for (int t = 0; t < 23; ++t) P[t] = 0.0f;
    #pragma unroll
    for (int s = 22; s >= 0; --s) {
      const float base = nl * Gt[(g[s] << 6) + q];
      const float cs = cfv[s] * (base - P[s]);
      carr[s] = cs;
      #pragma unroll
      for (int t = 0; t < s; ++t)
        P[t] = fmaf(cs, Gt[(g[t] << 6) + g[s]], P[t]);
    }
    float* wrow = lds + W32_L + ab * 64;
    #pragma unroll
    for (int t = 0; t < 23; ++t)
      atomicAdd(&wrow[g[t]], carr[t]);   // ds_add_f32, single owner lane per row
  }
  __syncthreads();

  // ---- Convert W32 -> WH/WL (wave handles its 16 rows) ----
  {
    const int c4 = (lane & 15) * 4;
    unsigned short* whp = (unsigned short*)(lds + WH_L);
    unsigned short* wlp = (unsigned short*)(lds + WL_L);
    #pragma unroll
    for (int i = 0; i < 4; ++i) {
      const int row = wv * 16 + (lane >> 4) + i * 4;
      const float4 f = *(const float4*)(lds + W32_L + row * 64 + c4);
      ushort4 h, l2;
      h.x = bf_hi(f.x); h.y = bf_hi(f.y); h.z = bf_hi(f.z); h.w = bf_hi(f.w);
      l2.x = bf_hi(f.x - __uint_as_float((unsigned)h.x << 16));
      l2.y = bf_hi(f.y - __uint_as_float((unsigned)h.y << 16));
      l2.z = bf_hi(f.z - __uint_as_float((unsigned)h.z << 16));
      l2.w = bf_hi(f.w - __uint_as_float((unsigned)h.w << 16));
      *(ushort4*)(whp + row * 72 + c4) = h;
      *(ushort4*)(wlp + row * 72 + c4) = l2;
    }
  }
  __syncthreads();

  // ---- Phase B: MFMA ----
  const int cl = lane & 15;
  const int q4 = lane >> 4;
  const unsigned short* whp = (const unsigned short*)(lds + WH_L);
  const unsigned short* wlp = (const unsigned short*)(lds + WL_L);
  const unsigned short* bhp = (const unsigned short*)(lds + WKTH_L);
  const unsigned short* blp = (const unsigned short*)(lds + WKTL_L);

  const int arow = wv * 16 + cl;   // A fragment: row = lane&15 (m89 mapping)
  const short8v ah0 = *(const short8v*)(whp + arow * 72 + q4 * 8);
  const short8v ah1 = *(const short8v*)(whp + arow * 72 + 32 + q4 * 8);
  const short8v al0 = *(const short8v*)(wlp + arow * 72 + q4 * 8);
  const short8v al1 = *(const short8v*)(wlp + arow * 72 + 32 + q4 * 8);

  #pragma unroll
  for (int ct = 0; ct < 4; ++ct) {
    const int col = ct * 16 + cl;  // B fragment: col = lane&15, k rows (lane>>4)*8..+7
    const short8v bh0 = *(const short8v*)(bhp + col * 72 + q4 * 8);
    const short8v bh1 = *(const short8v*)(bhp + col * 72 + 32 + q4 * 8);
    const short8v bl0 = *(const short8v*)(blp + col * 72 + q4 * 8);
    const short8v bl1 = *(const short8v*)(blp + col * 72 + 32 + q4 * 8);
    const float b2v = lds[TAIL_L + 64 + col];
    f32x4 acc = {b2v, b2v, b2v, b2v};
    acc = __builtin_amdgcn_mfma_f32_16x16x32_bf16(ah0, bh0, acc, 0, 0, 0);
    acc = __builtin_amdgcn_mfma_f32_16x16x32_bf16(ah1, bh1, acc, 0, 0, 0);
    acc = __builtin_amdgcn_mfma_f32_16x16x32_bf16(al0, bh0, acc, 0, 0, 0);
    acc = __builtin_amdgcn_mfma_f32_16x16x32_bf16(al1, bh1, acc, 0, 0, 0);
    acc = __builtin_amdgcn_mfma_f32_16x16x32_bf16(ah0, bl0, acc, 0, 0, 0);
    acc = __builtin_amdgcn_mfma_f32_16x16x32_bf16(ah1, bl1, acc, 0, 0, 0);
    // D: col = lane&15, row = (lane>>4)*4 + reg  (m89-verified)
    #pragma unroll
    for (int rr = 0; rr < 4; ++rr)
      out[(batch0 + wv * 16 + q4 * 4 + rr) * V_SZ + col] = acc[rr];
  }
}

// ---------------------------------------------------------------------------
extern "C" void kernel_launch(void* const* d_in, const int* in_sizes, int n_in,
                              void* d_out, int out_size, void* d_ws, size_t ws_size,
                              hipStream_t stream)
{
  const int*   seq          = (const int*)d_in[0];
  const float* embed        = (const float*)d_in[1];
  const float* w1           = (const float*)d_in[2];
  const float* b1           = (const float*)d_in[3];
  const float* w2           = (const float*)d_in[4];
  const float* b2           = (const float*)d_in[5];
  const float* ln_g         = (const float*)d_in[6];
  const float* ln_b         = (const float*)d_in[7];
  const float* rp_w         = (const float*)d_in[8];
  const float* rp_b         = (const float*)d_in[9];
  const float* out_w        = (const float*)d_in[10];
  const float* out_b        = (const float*)d_in[11];
  const float* alpha_logits = (const float*)d_in[12];
  float* ws   = (float*)d_ws;
  float* outp = (float*)d_out;

  hipLaunchKernelGGL(k_tab, dim3(V_SZ + 1), dim3(64), 0, stream,
                     embed, w1, b1, w2, b2, ln_g, ln_b,
                     rp_w, rp_b, out_w, out_b, alpha_logits, ws);
  hipLaunchKernelGGL(k_gw, dim3(V_SZ), dim3(64), 0, stream, ws);
  hipLaunchKernelGGL(k_scan, dim3(B_SZ / 64), dim3(256), 0, stream,
                     seq, ws, outp);
}